// Round 6
// baseline (133.633 us; speedup 1.0000x reference)
//
#include <hip/hip_runtime.h>
#include <hip/hip_bf16.h>

// Problem: B=8, A=512, IN=OUT=1024, N_OPT=16, fp32 in/out.
// out[b,a,i] = sum_j (sum_n sp[b,n] W[n,i,j]) x[b,a,j] + sum_n sp[b,n] bias[n,i]
//
// Strategy: mix weights once (reads W 64MB exactly once), cast to bf16,
// then 8 batched MFMA GEMMs (C = X * Wm^T), bias folded into epilogue.
//
// R5->R6: hybrid operand routing. B (wm) stays LDS-staged (8x cross-block
// reuse); A fragments load directly global->VGPR from k-octet-transposed
// xt[b][c][r][8] (c=k/8). A-loads issue before the barrier and land during
// its vmcnt drain -> post-barrier critical path is only B ds_read -> MFMA.
// LDS traffic/iter halves (48->24 KB). Prep writes xt with 256B-coalesced
// segments (lanes ordered r-fast within c), unlike R4's scattered transpose.

#define B_SZ 8
#define A_SZ 512
#define IN_F 1024
#define OUT_F 1024
#define N_OPT 16

typedef short short8 __attribute__((ext_vector_type(8)));
typedef float floatx4 __attribute__((ext_vector_type(4)));

__device__ __forceinline__ unsigned short f2bf(float f) {
    unsigned int u = __builtin_bit_cast(unsigned int, f);
    u += 0x7fffu + ((u >> 16) & 1u);   // RNE; inputs finite
    return (unsigned short)(u >> 16);
}

#define GLOBAL_LOAD_LDS16(g, l)                                                    \
    __builtin_amdgcn_global_load_lds(                                              \
        (const __attribute__((address_space(1))) void*)(g),                        \
        (__attribute__((address_space(3))) void*)(l), 16, 0, 0)

// ---------------------------------------------------------------------------
// Kernel 1: prep (1032 blocks).
//   blocks [0,1024):   weight mixing -> bf16 wm [8][1024][1024] (coalesced)
//                      + x fp32->bf16 transpose -> xt[b][c][r][8]
//   blocks [1024,1032): bias mixing -> fp32 bmixed [8][1024]
// ---------------------------------------------------------------------------
__global__ __launch_bounds__(256) void selin_prep(
    const float* __restrict__ x, const float* __restrict__ sp,
    const float* __restrict__ weight, const float* __restrict__ bias,
    unsigned short* __restrict__ wm, unsigned short* __restrict__ xt,
    float* __restrict__ bmixed)
{
    const int bid = blockIdx.x;
    const int tid = threadIdx.x;

    if (bid < 1024) {
        __shared__ float sps[B_SZ * N_OPT];
        if (tid < B_SZ * N_OPT) sps[tid] = sp[tid];
        __syncthreads();
        // --- weight mixing: fully coalesced read/write streams ---
        const int e4 = bid * 256 + tid;              // float4 index into 1024x1024
        const float4* w4 = (const float4*)weight;
        float4 w[N_OPT];
#pragma unroll
        for (int n = 0; n < N_OPT; n++)
            w[n] = w4[(size_t)n * (IN_F * OUT_F / 4) + e4];
#pragma unroll
        for (int b = 0; b < B_SZ; b++) {
            float ax = 0.f, ay = 0.f, az = 0.f, aw = 0.f;
#pragma unroll
            for (int n = 0; n < N_OPT; n++) {
                float s = sps[b * N_OPT + n];
                ax += s * w[n].x; ay += s * w[n].y;
                az += s * w[n].z; aw += s * w[n].w;
            }
            ushort4 o = make_ushort4(f2bf(ax), f2bf(ay), f2bf(az), f2bf(aw));
            ((ushort4*)wm)[(size_t)b * (IN_F * OUT_F / 4) + e4] = o;
        }
        // --- x transpose: 524288 chunks (32B read, 16B write), 2/thread ---
        // wave covers 16r x 4c; lanes r-fast -> 256B write segments.
        const float4* x4 = (const float4*)x;
#pragma unroll
        for (int j = 0; j < 2; j++) {
            const int g  = bid * 256 + tid + j * 262144;
            const int wg = g >> 6, l = g & 63;
            const int b  = wg >> 10, rem = wg & 1023;
            const int r  = ((rem & 31) << 4) + (l & 15);
            const int c  = ((rem >> 5) << 2) + (l >> 4);
            const size_t ridx = ((size_t)(b * 512 + r)) * 256 + c * 2;
            float4 v0 = x4[ridx], v1 = x4[ridx + 1];
            short8 o;
            o[0] = (short)f2bf(v0.x); o[1] = (short)f2bf(v0.y);
            o[2] = (short)f2bf(v0.z); o[3] = (short)f2bf(v0.w);
            o[4] = (short)f2bf(v1.x); o[5] = (short)f2bf(v1.y);
            o[6] = (short)f2bf(v1.z); o[7] = (short)f2bf(v1.w);
            *(short8*)(xt + ((size_t)b * 65536 + (size_t)c * 512 + r) * 8) = o;
        }
    } else {
        __shared__ float sps[B_SZ * N_OPT];
        if (tid < B_SZ * N_OPT) sps[tid] = sp[tid];
        __syncthreads();
        const int idx = (bid - 1024) * 256 + tid;    // float4 over 8x1024
        const int b = idx >> 8, i4 = idx & 255;
        const float4* bias4 = (const float4*)bias;
        float ax = 0.f, ay = 0.f, az = 0.f, aw = 0.f;
#pragma unroll
        for (int n = 0; n < N_OPT; n++) {
            float s = sps[b * N_OPT + n];
            float4 v = bias4[n * 256 + i4];
            ax += s * v.x; ay += s * v.y; az += s * v.z; aw += s * v.w;
        }
        ((float4*)bmixed)[idx] = make_float4(ax, ay, az, aw);
    }
}

// ---------------------------------------------------------------------------
// Kernel 2: batched GEMM, C[b] = X[b] * Wm[b]^T + bias.
// Tile 64x64, BK=64. B staged via global_load_lds (two 32-k panels, m97
// bank-safe layout); A fragments loaded directly global->VGPR from xt.
// 4 waves 2x2, each 32x32 = 2x2 frags of 16x16x32 MFMA.
// Grid: 1024 blocks (4/CU, 8KB LDS); b = bid&7 XCD-L2 swizzle.
// ---------------------------------------------------------------------------
__global__ __launch_bounds__(256) void selin_gemm(
    const unsigned short* __restrict__ xt, const unsigned short* __restrict__ wm,
    const float* __restrict__ bmixed, float* __restrict__ out)
{
    __shared__ __align__(16) unsigned short Bs[2][64 * 32];   // 2 x 4 KB

    const int tid = threadIdx.x;
    const int bid = blockIdx.x;
    const int b   = bid & 7;          // XCD swizzle: same b -> same XCD
    const int t   = bid >> 3;         // 0..127
    const int mb  = t & 7;            // 8 m-blocks of 64 rows
    const int nb  = t >> 3;           // 16 n-blocks of 64 cols
    const int m0  = mb * 64, n0 = nb * 64;

    const unsigned short* Bg = wm + ((size_t)b * OUT_F + n0) * IN_F;
    const int ga = (tid >> 2) * IN_F + (tid & 3) * 8;   // B staging chunk

    const int lane = tid & 63;
    const int wv   = tid >> 6;
    const int wmi  = wv >> 1, wni = wv & 1;   // 2x2 wave grid: 32 rows x 32 cols
    const int lm   = lane & 15, kq = lane >> 4;

    // A direct-load bases: xt[b][c][r][8], chunk (c,r) at (c*512+r)*8 ushorts.
    // frag (mi,kh,it): row = m0+wmi*32+mi*16+lm, c = it*8+kh*4+kq.
    const unsigned short* xtb = xt + (size_t)b * 524288;
    const unsigned short* ap[2];
#pragma unroll
    for (int mi = 0; mi < 2; mi++)
        ap[mi] = xtb + (size_t)kq * 4096 + (size_t)(m0 + wmi * 32 + mi * 16 + lm) * 8;

    floatx4 acc[2][2];
#pragma unroll
    for (int i = 0; i < 2; i++)
#pragma unroll
        for (int j = 0; j < 2; j++)
            acc[i][j] = (floatx4){0.f, 0.f, 0.f, 0.f};

    for (int it = 0; it < 16; it++) {
        const int k0 = it * 64;
        GLOBAL_LOAD_LDS16(Bg + ga + k0,      &Bs[0][tid * 8]);
        GLOBAL_LOAD_LDS16(Bg + ga + k0 + 32, &Bs[1][tid * 8]);

        // A fragments: plain global loads, land during the barrier drain
        short8 a[2][2];
        const size_t coff = (size_t)it * 32768;
#pragma unroll
        for (int mi = 0; mi < 2; mi++) {
            a[mi][0] = *(const short8*)(ap[mi] + coff);
            a[mi][1] = *(const short8*)(ap[mi] + coff + 16384);
        }
        __syncthreads();   // B staging complete (drains vmcnt, incl. A)

#pragma unroll
        for (int kh = 0; kh < 2; kh++) {
            short8 bb[2];
#pragma unroll
            for (int ni = 0; ni < 2; ni++)
                bb[ni] = *(const short8*)&Bs[kh][(wni * 32 + ni * 16 + lm) * 32 + kq * 8];
#pragma unroll
            for (int mi = 0; mi < 2; mi++)
#pragma unroll
                for (int ni = 0; ni < 2; ni++)
                    acc[mi][ni] = __builtin_amdgcn_mfma_f32_16x16x32_bf16(
                        a[mi][kh], bb[ni], acc[mi][ni], 0, 0, 0);
        }
        __syncthreads();   // B reads done before next staging overwrites LDS
    }

    // epilogue: C/D layout col=lane&15, row=(lane>>4)*4+reg
#pragma unroll
    for (int ni = 0; ni < 2; ni++) {
        const int gcol = n0 + wni * 32 + ni * 16 + lm;
        const float bv = bmixed[b * OUT_F + gcol];
#pragma unroll
        for (int mi = 0; mi < 2; mi++) {
            const int grow = m0 + wmi * 32 + mi * 16 + kq * 4;
            float* op = out + ((size_t)b * A_SZ + grow) * OUT_F + gcol;
#pragma unroll
            for (int r = 0; r < 4; r++)
                op[(size_t)r * OUT_F] = acc[mi][ni][r] + bv;
        }
    }
}

extern "C" void kernel_launch(void* const* d_in, const int* in_sizes, int n_in,
                              void* d_out, int out_size, void* d_ws, size_t ws_size,
                              hipStream_t stream) {
    const float* x      = (const float*)d_in[0];  // [8,512,1024]
    const float* sp     = (const float*)d_in[1];  // [8,16]
    const float* weight = (const float*)d_in[2];  // [16,1024,1024]
    const float* bias   = (const float*)d_in[3];  // [16,1024]
    float* out = (float*)d_out;                   // [8,512,1024]

    // workspace layout: wm bf16 16MB | xt bf16 8MB | bmixed fp32 32KB
    unsigned short* wm  = (unsigned short*)d_ws;
    unsigned short* xt  = wm + (size_t)B_SZ * OUT_F * IN_F;
    float* bmixed       = (float*)(xt + (size_t)B_SZ * A_SZ * IN_F);

    selin_prep<<<1032, 256, 0, stream>>>(x, sp, weight, bias, wm, xt, bmixed);
    selin_gemm<<<1024, 256, 0, stream>>>(xt, wm, bmixed, out);
}

// Round 7
// 132.059 us; speedup vs baseline: 1.0119x; 1.0119x over previous
//
#include <hip/hip_runtime.h>
#include <hip/hip_bf16.h>

// Problem: B=8, A=512, IN=OUT=1024, N_OPT=16, fp32 in/out.
// out[b,a,i] = sum_j (sum_n sp[b,n] W[n,i,j]) x[b,a,j] + sum_n sp[b,n] bias[n,i]
//
// Strategy: mix weights once (reads W 64MB exactly once), cast to bf16,
// then 8 batched MFMA GEMMs (C = X * Wm^T), bias folded into epilogue.
//
// R6->R7: revert R6's hybrid A-direct path (duplicated A fetches + scattered
// prep writes cost +3.6us). Back to R5 structure; BK 64 -> 128 (four 32-k
// sub-panels, same bank-safe layout): barrier pairs 16 -> 8. LDS 32KB/block,
// still 4 blocks/CU (128KB/CU of 160KB).

#define B_SZ 8
#define A_SZ 512
#define IN_F 1024
#define OUT_F 1024
#define N_OPT 16

typedef short short8 __attribute__((ext_vector_type(8)));
typedef float floatx4 __attribute__((ext_vector_type(4)));

__device__ __forceinline__ unsigned short f2bf(float f) {
    unsigned int u = __builtin_bit_cast(unsigned int, f);
    u += 0x7fffu + ((u >> 16) & 1u);   // RNE; inputs finite
    return (unsigned short)(u >> 16);
}

#define GLOBAL_LOAD_LDS16(g, l)                                                    \
    __builtin_amdgcn_global_load_lds(                                              \
        (const __attribute__((address_space(1))) void*)(g),                        \
        (__attribute__((address_space(3))) void*)(l), 16, 0, 0)

// ---------------------------------------------------------------------------
// Kernel 1: prep (1032 blocks).
//   blocks [0,1024):   weight mixing -> bf16 wm [8][1024][1024]  (coalesced)
//                      + x fp32->bf16 slice (4 float4/thread, streamed)
//   blocks [1024,1032): bias mixing -> fp32 bmixed [8][1024]
// ---------------------------------------------------------------------------
__global__ __launch_bounds__(256) void selin_prep(
    const float* __restrict__ x, const float* __restrict__ sp,
    const float* __restrict__ weight, const float* __restrict__ bias,
    unsigned short* __restrict__ wm, unsigned short* __restrict__ xbf,
    float* __restrict__ bmixed)
{
    const int bid = blockIdx.x;
    const int tid = threadIdx.x;

    if (bid < 1024) {
        __shared__ float sps[B_SZ * N_OPT];
        if (tid < B_SZ * N_OPT) sps[tid] = sp[tid];
        __syncthreads();
        // --- weight mixing: fully coalesced read/write streams ---
        const int e4 = bid * 256 + tid;              // float4 index into 1024x1024
        const float4* w4 = (const float4*)weight;
        float4 w[N_OPT];
#pragma unroll
        for (int n = 0; n < N_OPT; n++)
            w[n] = w4[(size_t)n * (IN_F * OUT_F / 4) + e4];
#pragma unroll
        for (int b = 0; b < B_SZ; b++) {
            float ax = 0.f, ay = 0.f, az = 0.f, aw = 0.f;
#pragma unroll
            for (int n = 0; n < N_OPT; n++) {
                float s = sps[b * N_OPT + n];
                ax += s * w[n].x; ay += s * w[n].y;
                az += s * w[n].z; aw += s * w[n].w;
            }
            ushort4 o = make_ushort4(f2bf(ax), f2bf(ay), f2bf(az), f2bf(aw));
            ((ushort4*)wm)[(size_t)b * (IN_F * OUT_F / 4) + e4] = o;
        }
        // --- x conversion slice: 1,048,576 float4 over 1024 blocks ---
#pragma unroll
        for (int j = 0; j < 4; j++) {
            const int idx = bid * 1024 + j * 256 + tid;
            float4 v = ((const float4*)x)[idx];
            ((ushort4*)xbf)[idx] =
                make_ushort4(f2bf(v.x), f2bf(v.y), f2bf(v.z), f2bf(v.w));
        }
    } else {
        __shared__ float sps[B_SZ * N_OPT];
        if (tid < B_SZ * N_OPT) sps[tid] = sp[tid];
        __syncthreads();
        const int idx = (bid - 1024) * 256 + tid;    // float4 over 8x1024
        const int b = idx >> 8, i4 = idx & 255;
        const float4* bias4 = (const float4*)bias;
        float ax = 0.f, ay = 0.f, az = 0.f, aw = 0.f;
#pragma unroll
        for (int n = 0; n < N_OPT; n++) {
            float s = sps[b * N_OPT + n];
            float4 v = bias4[n * 256 + i4];
            ax += s * v.x; ay += s * v.y; az += s * v.z; aw += s * v.w;
        }
        ((float4*)bmixed)[idx] = make_float4(ax, ay, az, aw);
    }
}

// ---------------------------------------------------------------------------
// Kernel 2: batched GEMM, C[b] = X[b] (512x1024) * Wm[b]^T (1024x1024) + bias.
// Tile 64x64, BK=128 staged as four 32-k sub-panels (m97 bank-safe 64B row
// stride). 4 waves in 2x2; each wave 32x32 = 2x2 frags of 16x16x32 MFMA,
// 4 k-halves per barrier pair -> 8 barrier pairs (vs 16 at BK=64).
// Grid: 1024 blocks (4/CU, 32KB LDS); b = bid&7 XCD-L2 swizzle.
// ---------------------------------------------------------------------------
__global__ __launch_bounds__(256) void selin_gemm(
    const unsigned short* __restrict__ xbf, const unsigned short* __restrict__ wm,
    const float* __restrict__ bmixed, float* __restrict__ out)
{
    __shared__ __align__(16) unsigned short As[4][64 * 32];   // 4 x 4 KB
    __shared__ __align__(16) unsigned short Bs[4][64 * 32];   // 4 x 4 KB

    const int tid = threadIdx.x;
    const int bid = blockIdx.x;
    const int b   = bid & 7;          // XCD swizzle: same b -> same XCD
    const int t   = bid >> 3;         // 0..127
    const int mb  = t & 7;            // 8 m-blocks of 64 rows
    const int nb  = t >> 3;           // 16 n-blocks of 64 cols
    const int m0  = mb * 64, n0 = nb * 64;

    const unsigned short* Ag = xbf + ((size_t)b * A_SZ  + m0) * IN_F;
    const unsigned short* Bg = wm  + ((size_t)b * OUT_F + n0) * IN_F;

    // 64x32 sub-panel = 4KB = 256 16B-chunks; one chunk per thread per panel.
    const int ga = (tid >> 2) * IN_F + (tid & 3) * 8;   // + k at use

    const int lane = tid & 63;
    const int wv   = tid >> 6;
    const int wmi  = wv >> 1, wni = wv & 1;   // 2x2 wave grid: 32 rows x 32 cols
    const int lm   = lane & 15, kq = lane >> 4;

    floatx4 acc[2][2];
#pragma unroll
    for (int i = 0; i < 2; i++)
#pragma unroll
        for (int j = 0; j < 2; j++)
            acc[i][j] = (floatx4){0.f, 0.f, 0.f, 0.f};

    for (int k0 = 0; k0 < IN_F; k0 += 128) {
#pragma unroll
        for (int p = 0; p < 4; p++) {
            GLOBAL_LOAD_LDS16(Ag + ga + k0 + p * 32, &As[p][tid * 8]);
            GLOBAL_LOAD_LDS16(Bg + ga + k0 + p * 32, &Bs[p][tid * 8]);
        }
        __syncthreads();   // staging complete (barrier drains vmcnt)

#pragma unroll
        for (int kh = 0; kh < 4; kh++) {
            short8 a[2], bb[2];
#pragma unroll
            for (int mi = 0; mi < 2; mi++)
                a[mi] = *(const short8*)&As[kh][(wmi * 32 + mi * 16 + lm) * 32 + kq * 8];
#pragma unroll
            for (int ni = 0; ni < 2; ni++)
                bb[ni] = *(const short8*)&Bs[kh][(wni * 32 + ni * 16 + lm) * 32 + kq * 8];

#pragma unroll
            for (int mi = 0; mi < 2; mi++)
#pragma unroll
                for (int ni = 0; ni < 2; ni++)
                    acc[mi][ni] = __builtin_amdgcn_mfma_f32_16x16x32_bf16(
                        a[mi], bb[ni], acc[mi][ni], 0, 0, 0);
        }
        __syncthreads();   // reads done before next staging overwrites LDS
    }

    // epilogue: C/D layout col=lane&15, row=(lane>>4)*4+reg
#pragma unroll
    for (int ni = 0; ni < 2; ni++) {
        const int gcol = n0 + wni * 32 + ni * 16 + lm;
        const float bv = bmixed[b * OUT_F + gcol];
#pragma unroll
        for (int mi = 0; mi < 2; mi++) {
            const int grow = m0 + wmi * 32 + mi * 16 + kq * 4;
            float* op = out + ((size_t)b * A_SZ + grow) * OUT_F + gcol;
#pragma unroll
            for (int r = 0; r < 4; r++)
                op[(size_t)r * OUT_F] = acc[mi][ni][r] + bv;
        }
    }
}

extern "C" void kernel_launch(void* const* d_in, const int* in_sizes, int n_in,
                              void* d_out, int out_size, void* d_ws, size_t ws_size,
                              hipStream_t stream) {
    const float* x      = (const float*)d_in[0];  // [8,512,1024]
    const float* sp     = (const float*)d_in[1];  // [8,16]
    const float* weight = (const float*)d_in[2];  // [16,1024,1024]
    const float* bias   = (const float*)d_in[3];  // [16,1024]
    float* out = (float*)d_out;                   // [8,512,1024]

    // workspace layout: wm bf16 16MB | xbf bf16 8MB | bmixed fp32 32KB
    unsigned short* wm  = (unsigned short*)d_ws;
    unsigned short* xbf = wm + (size_t)B_SZ * OUT_F * IN_F;
    float* bmixed       = (float*)(xbf + (size_t)B_SZ * A_SZ * IN_F);

    selin_prep<<<1032, 256, 0, stream>>>(x, sp, weight, bias, wm, xbf, bmixed);
    selin_gemm<<<1024, 256, 0, stream>>>(xbf, wm, bmixed, out);
}

// Round 9
// 130.415 us; speedup vs baseline: 1.0247x; 1.0126x over previous
//
#include <hip/hip_runtime.h>
#include <hip/hip_bf16.h>

// Problem: B=8, A=512, IN=OUT=1024, N_OPT=16, fp32 in/out.
// out[b,a,i] = sum_j (sum_n sp[b,n] W[n,i,j]) x[b,a,j] + sum_n sp[b,n] bias[n,i]
//
// Strategy: mix weights once (reads W 64MB exactly once), cast to bf16,
// then 8 batched MFMA GEMMs (C = X * Wm^T), bias folded into epilogue.
//
// R8->R9: clean revert to R5, the verified best (129.96us). Cooperative
// launch (R8) silently fails under harness graph capture; flatmm (R4),
// hybrid A-direct (R6), and BK=128 (R7) all regressed. R5 = 64x64 tile,
// BK=64 as two 32-k bank-safe sub-panels, 1024 blocks (4/CU), XCD swizzle.

#define B_SZ 8
#define A_SZ 512
#define IN_F 1024
#define OUT_F 1024
#define N_OPT 16

typedef short short8 __attribute__((ext_vector_type(8)));
typedef float floatx4 __attribute__((ext_vector_type(4)));

__device__ __forceinline__ unsigned short f2bf(float f) {
    unsigned int u = __builtin_bit_cast(unsigned int, f);
    u += 0x7fffu + ((u >> 16) & 1u);   // RNE; inputs finite
    return (unsigned short)(u >> 16);
}

#define GLOBAL_LOAD_LDS16(g, l)                                                    \
    __builtin_amdgcn_global_load_lds(                                              \
        (const __attribute__((address_space(1))) void*)(g),                        \
        (__attribute__((address_space(3))) void*)(l), 16, 0, 0)

// ---------------------------------------------------------------------------
// Kernel 1: prep (1032 blocks).
//   blocks [0,1024):   weight mixing -> bf16 wm [8][1024][1024]  (coalesced)
//                      + x fp32->bf16 slice (4 float4/thread, streamed)
//   blocks [1024,1032): bias mixing -> fp32 bmixed [8][1024]
// ---------------------------------------------------------------------------
__global__ __launch_bounds__(256) void selin_prep(
    const float* __restrict__ x, const float* __restrict__ sp,
    const float* __restrict__ weight, const float* __restrict__ bias,
    unsigned short* __restrict__ wm, unsigned short* __restrict__ xbf,
    float* __restrict__ bmixed)
{
    const int bid = blockIdx.x;
    const int tid = threadIdx.x;

    if (bid < 1024) {
        __shared__ float sps[B_SZ * N_OPT];
        if (tid < B_SZ * N_OPT) sps[tid] = sp[tid];
        __syncthreads();
        // --- weight mixing: fully coalesced read/write streams ---
        const int e4 = bid * 256 + tid;              // float4 index into 1024x1024
        const float4* w4 = (const float4*)weight;
        float4 w[N_OPT];
#pragma unroll
        for (int n = 0; n < N_OPT; n++)
            w[n] = w4[(size_t)n * (IN_F * OUT_F / 4) + e4];
#pragma unroll
        for (int b = 0; b < B_SZ; b++) {
            float ax = 0.f, ay = 0.f, az = 0.f, aw = 0.f;
#pragma unroll
            for (int n = 0; n < N_OPT; n++) {
                float s = sps[b * N_OPT + n];
                ax += s * w[n].x; ay += s * w[n].y;
                az += s * w[n].z; aw += s * w[n].w;
            }
            ushort4 o = make_ushort4(f2bf(ax), f2bf(ay), f2bf(az), f2bf(aw));
            ((ushort4*)wm)[(size_t)b * (IN_F * OUT_F / 4) + e4] = o;
        }
        // --- x conversion slice: 1,048,576 float4 over 1024 blocks ---
#pragma unroll
        for (int j = 0; j < 4; j++) {
            const int idx = bid * 1024 + j * 256 + tid;
            float4 v = ((const float4*)x)[idx];
            ((ushort4*)xbf)[idx] =
                make_ushort4(f2bf(v.x), f2bf(v.y), f2bf(v.z), f2bf(v.w));
        }
    } else {
        __shared__ float sps[B_SZ * N_OPT];
        if (tid < B_SZ * N_OPT) sps[tid] = sp[tid];
        __syncthreads();
        const int idx = (bid - 1024) * 256 + tid;    // float4 over 8x1024
        const int b = idx >> 8, i4 = idx & 255;
        const float4* bias4 = (const float4*)bias;
        float ax = 0.f, ay = 0.f, az = 0.f, aw = 0.f;
#pragma unroll
        for (int n = 0; n < N_OPT; n++) {
            float s = sps[b * N_OPT + n];
            float4 v = bias4[n * 256 + i4];
            ax += s * v.x; ay += s * v.y; az += s * v.z; aw += s * v.w;
        }
        ((float4*)bmixed)[idx] = make_float4(ax, ay, az, aw);
    }
}

// ---------------------------------------------------------------------------
// Kernel 2: batched GEMM, C[b] = X[b] (512x1024) * Wm[b]^T (1024x1024) + bias.
// Tile 64x64, BK=64 staged as two 32-k sub-panels (m97 bank-safe 64B row
// stride). 4 waves in 2x2; each wave 32x32 = 2x2 frags of 16x16x32 MFMA,
// 2 k-halves per barrier pair -> 16 barrier pairs (vs 32 at BK=32).
// Grid: 1024 blocks (4/CU, 16KB LDS); b = bid&7 XCD-L2 swizzle.
// ---------------------------------------------------------------------------
__global__ __launch_bounds__(256) void selin_gemm(
    const unsigned short* __restrict__ xbf, const unsigned short* __restrict__ wm,
    const float* __restrict__ bmixed, float* __restrict__ out)
{
    __shared__ __align__(16) unsigned short As[2][64 * 32];   // 2 x 4 KB
    __shared__ __align__(16) unsigned short Bs[2][64 * 32];   // 2 x 4 KB

    const int tid = threadIdx.x;
    const int bid = blockIdx.x;
    const int b   = bid & 7;          // XCD swizzle: same b -> same XCD
    const int t   = bid >> 3;         // 0..127
    const int mb  = t & 7;            // 8 m-blocks of 64 rows
    const int nb  = t >> 3;           // 16 n-blocks of 64 cols
    const int m0  = mb * 64, n0 = nb * 64;

    const unsigned short* Ag = xbf + ((size_t)b * A_SZ  + m0) * IN_F;
    const unsigned short* Bg = wm  + ((size_t)b * OUT_F + n0) * IN_F;

    // 64x32 sub-panel = 4KB = 256 16B-chunks; one chunk per thread per panel.
    const int ga = (tid >> 2) * IN_F + (tid & 3) * 8;   // + k at use

    const int lane = tid & 63;
    const int wv   = tid >> 6;
    const int wmi  = wv >> 1, wni = wv & 1;   // 2x2 wave grid: 32 rows x 32 cols
    const int lm   = lane & 15, kq = lane >> 4;

    floatx4 acc[2][2];
#pragma unroll
    for (int i = 0; i < 2; i++)
#pragma unroll
        for (int j = 0; j < 2; j++)
            acc[i][j] = (floatx4){0.f, 0.f, 0.f, 0.f};

    for (int k0 = 0; k0 < IN_F; k0 += 64) {
        GLOBAL_LOAD_LDS16(Ag + ga + k0,      &As[0][tid * 8]);
        GLOBAL_LOAD_LDS16(Ag + ga + k0 + 32, &As[1][tid * 8]);
        GLOBAL_LOAD_LDS16(Bg + ga + k0,      &Bs[0][tid * 8]);
        GLOBAL_LOAD_LDS16(Bg + ga + k0 + 32, &Bs[1][tid * 8]);
        __syncthreads();   // staging complete (barrier drains vmcnt)

#pragma unroll
        for (int kh = 0; kh < 2; kh++) {
            short8 a[2], bb[2];
#pragma unroll
            for (int mi = 0; mi < 2; mi++)
                a[mi] = *(const short8*)&As[kh][(wmi * 32 + mi * 16 + lm) * 32 + kq * 8];
#pragma unroll
            for (int ni = 0; ni < 2; ni++)
                bb[ni] = *(const short8*)&Bs[kh][(wni * 32 + ni * 16 + lm) * 32 + kq * 8];

#pragma unroll
            for (int mi = 0; mi < 2; mi++)
#pragma unroll
                for (int ni = 0; ni < 2; ni++)
                    acc[mi][ni] = __builtin_amdgcn_mfma_f32_16x16x32_bf16(
                        a[mi], bb[ni], acc[mi][ni], 0, 0, 0);
        }
        __syncthreads();   // reads done before next staging overwrites LDS
    }

    // epilogue: C/D layout col=lane&15, row=(lane>>4)*4+reg
#pragma unroll
    for (int ni = 0; ni < 2; ni++) {
        const int gcol = n0 + wni * 32 + ni * 16 + lm;
        const float bv = bmixed[b * OUT_F + gcol];
#pragma unroll
        for (int mi = 0; mi < 2; mi++) {
            const int grow = m0 + wmi * 32 + mi * 16 + kq * 4;
            float* op = out + ((size_t)b * A_SZ + grow) * OUT_F + gcol;
#pragma unroll
            for (int r = 0; r < 4; r++)
                op[(size_t)r * OUT_F] = acc[mi][ni][r] + bv;
        }
    }
}

extern "C" void kernel_launch(void* const* d_in, const int* in_sizes, int n_in,
                              void* d_out, int out_size, void* d_ws, size_t ws_size,
                              hipStream_t stream) {
    const float* x      = (const float*)d_in[0];  // [8,512,1024]
    const float* sp     = (const float*)d_in[1];  // [8,16]
    const float* weight = (const float*)d_in[2];  // [16,1024,1024]
    const float* bias   = (const float*)d_in[3];  // [16,1024]
    float* out = (float*)d_out;                   // [8,512,1024]

    // workspace layout: wm bf16 16MB | xbf bf16 8MB | bmixed fp32 32KB
    unsigned short* wm  = (unsigned short*)d_ws;
    unsigned short* xbf = wm + (size_t)B_SZ * OUT_F * IN_F;
    float* bmixed       = (float*)(xbf + (size_t)B_SZ * A_SZ * IN_F);

    selin_prep<<<1032, 256, 0, stream>>>(x, sp, weight, bias, wm, xbf, bmixed);
    selin_gemm<<<1024, 256, 0, stream>>>(xbf, wm, bmixed, out);
}